// Round 11
// baseline (71.190 us; speedup 1.0000x reference)
//
#include <hip/hip_runtime.h>
#include <hip/hip_bf16.h>
#include <math.h>

#define BB 256
#define NN 2048
#define MM 64
#define INF_ 128
#define HH 100
#define EPSF 1e-8f
#define PITCH 2056   // %32==8 -> summary writes at worst 2-way conflict (free)

struct Ptrs { const float* p[32]; };

__device__ __forceinline__ float softplusf(float x) {
    return fmaxf(x, 0.0f) + log1pf(__expf(-fabsf(x)));
}
__device__ __forceinline__ float sigmoidf(float x) {
    return 1.0f / (1.0f + __expf(-x));
}
// fast positive-base pow; |rel err| ~1e-6, far under the 1.36e-2 threshold
__device__ __forceinline__ float fpowf(float x, float g) {
    return __expf(g * __logf(x));
}

// block-wide (16 waves) reduction of two values
__device__ __forceinline__ void bredN(float& a, float& b, bool ismax, float* red)
{
    #pragma unroll
    for (int m = 32; m; m >>= 1) {
        float ta = __shfl_xor(a, m), tb = __shfl_xor(b, m);
        if (ismax) { a = fmaxf(a, ta); b = fmaxf(b, tb); }
        else       { a += ta; b += tb; }
    }
    const int wid = threadIdx.x >> 6;
    if ((threadIdx.x & 63) == 0) { red[wid] = a; red[16 + wid] = b; }
    __syncthreads();
    float ra = red[0], rb = red[16];
    #pragma unroll
    for (int w = 1; w < 16; ++w) {
        if (ismax) { ra = fmaxf(ra, red[w]); rb = fmaxf(rb, red[16 + w]); }
        else       { ra += red[w]; rb += red[16 + w]; }
    }
    __syncthreads();
    a = ra; b = rb;
}

// ---- phase-B per-row processing: 16-lane group, 4 floats/lane -------------
#define PROC_B(V_, IT_)                                                     \
    {                                                                       \
        const int n = (IT_) * 64 + g16;                                     \
        float f[4] = {V_.x, V_.y, V_.z, V_.w};                              \
        float acc[8];                                                       \
        _Pragma("unroll")                                                   \
        for (int j = 0; j < 8; ++j) acc[j] = 0.f;                           \
        _Pragma("unroll")                                                   \
        for (int j = 0; j < 4; ++j) {                                       \
            const float m = f[j];                                           \
            const float em = ev[j] * m;                                     \
            acc[0] = fmaf(kw[j], m, acc[0]);                                \
            acc[1] = fmaf(m, m, acc[1]);                                    \
            acc[2] = fmaf(kr[j], m, acc[2]);                                \
            acc[3] = fmaf(kr[j], em, acc[3]);                               \
            acc[4] = fmaf(m, av[j] - em, acc[4]);                           \
            acc[5] = fmaf(em, fmaf(-2.f, av[j], em), acc[5]);               \
        }                                                                   \
        float k1[4];                                                        \
        _Pragma("unroll")                                                   \
        for (int k = 0; k < 4; ++k) {                                       \
            float snd = (l8 & 1) ? acc[2 * k] : acc[2 * k + 1];             \
            float rcv = __shfl_xor(snd, 1);                                 \
            k1[k] = ((l8 & 1) ? acc[2 * k + 1] : acc[2 * k]) + rcv;         \
        }                                                                   \
        float k2[2];                                                        \
        _Pragma("unroll")                                                   \
        for (int k = 0; k < 2; ++k) {                                       \
            float snd = (l8 & 2) ? k1[2 * k] : k1[2 * k + 1];               \
            float rcv = __shfl_xor(snd, 2);                                 \
            k2[k] = ((l8 & 2) ? k1[2 * k + 1] : k1[2 * k]) + rcv;           \
        }                                                                   \
        float snd = (l8 & 4) ? k2[0] : k2[1];                               \
        float rcv = __shfl_xor(snd, 4);                                     \
        float tot = ((l8 & 4) ? k2[1] : k2[0]) + rcv;                       \
        tot += __shfl_xor(tot, 8);        /* add other half of 16-group */  \
        if (l16 == 3) tot = kra_ - tot;   /* v1 = kra - d2 */               \
        if (l16 == 5) tot += saa_;        /* u2 = raw + saa */              \
        if (l16 < 6) summ6[l16 * PITCH + n] = tot;                          \
    }

// ---- phase-D per-row processing: 16-lane group, 4 floats/lane -------------
#define PROC_D(V_, IT_)                                                     \
    {                                                                       \
        const int n = (IT_) * 64 + g16;                                     \
        const float c1 = ratt[n];                                           \
        const float c2 = c1 * watt[n];                                      \
        a1[0] = fmaf(c1, V_.x, a1[0]);  a2[0] = fmaf(c2, V_.x, a2[0]);      \
        a1[1] = fmaf(c1, V_.y, a1[1]);  a2[1] = fmaf(c2, V_.y, a2[1]);      \
        a1[2] = fmaf(c1, V_.z, a1[2]);  a2[2] = fmaf(c2, V_.z, a2[2]);      \
        a1[3] = fmaf(c1, V_.w, a1[3]);  a2[3] = fmaf(c2, V_.w, a2[3]);      \
    }

// ---------------------------------------------------------------------------
// One block per batch row b (1024 thr = 16 waves; grid == CU count).
// Streaming phases use 16-lane groups / 4 floats per lane so the whole
// working set fits the 64-VGPR cap hipcc enforces for 1024-thr blocks
// (rounds 8-10: deeper per-lane tiles spill to scratch and wreck the
// pipeline -- WRITE_SIZE is the tell).
// ---------------------------------------------------------------------------
__global__ void __launch_bounds__(1024) k_fused(Ptrs in,
                                                const float* __restrict__ mb,
                                                float* __restrict__ out)
{
    __shared__ float xs[INF_];
    __shared__ float hs[HH];
    __shared__ float pk_w[MM], pk_r[MM], pe[MM], pa[MM];
    __shared__ float psc[20];
    __shared__ float summ6[6 * PITCH];   // 49.3 KB; aliased by wp1/wp2 in D
    __shared__ float ats[NN];
    __shared__ float watt[NN];
    __shared__ float ratt[NN];
    __shared__ float red[32];
    __shared__ float rv[64];

    const int b = blockIdx.x, tid = threadIdx.x;
    const int lane = tid & 63, wv = tid >> 6;       // 16 waves
    const int g16 = tid >> 4, l16 = tid & 15;       // 64 groups of 16
    const int l8 = l16 & 7;

    // ---------------- Phase A: params ----------------
    if (tid < INF_) xs[tid] = in.p[0][b * INF_ + tid];
    __syncthreads();

    if (tid < HH) {
        const float* Wc = in.p[1];
        float acc = in.p[2][tid];
        #pragma unroll 8
        for (int i = 0; i < INF_; ++i)
            acc = fmaf(xs[i], Wc[i * HH + tid], acc);
        hs[tid] = acc;
    }
    __syncthreads();

    if (wv < 4) {
        const int m = lane;
        const float* W; const float* bi;
        if      (wv == 0) { W = in.p[23]; bi = in.p[24]; }
        else if (wv == 1) { W = in.p[13]; bi = in.p[14]; }
        else if (wv == 2) { W = in.p[25]; bi = in.p[26]; }
        else              { W = in.p[27]; bi = in.p[28]; }
        float acc = bi[m];
        #pragma unroll 10
        for (int j = 0; j < HH; ++j)
            acc = fmaf(hs[j], W[j * 64 + m], acc);
        if      (wv == 0) pk_w[m] = acc;
        else if (wv == 1) pk_r[m] = acc;
        else if (wv == 2) pe[m]   = sigmoidf(acc);
        else              pa[m]   = acc;
    } else {
        const int s = wv - 4;
        const float* W; float bia; int strd = 1, c = 0;
        if      (s == 0) { W = in.p[15]; bia = in.p[16][0]; }
        else if (s == 1) { W = in.p[17]; bia = in.p[18][0]; }
        else if (s == 2) { W = in.p[19]; bia = in.p[20][0]; }
        else if (s == 3) { W = in.p[5];  bia = in.p[6][0]; }
        else if (s == 4) { W = in.p[7];  bia = in.p[8][0]; }
        else if (s == 5) { W = in.p[9];  bia = in.p[10][0]; }
        else if (s < 9)  { W = in.p[21]; c = s - 6; bia = in.p[22][c]; strd = 3; }
        else             { W = in.p[11]; c = s - 9; bia = in.p[12][c]; strd = 3; }
        float v = 0.f;
        if (lane < HH)      v = hs[lane] * W[lane * strd + c];
        if (lane < HH - 64) v = fmaf(hs[lane + 64], W[(lane + 64) * strd + c], v);
        #pragma unroll
        for (int m2 = 32; m2; m2 >>= 1) v += __shfl_xor(v, m2);
        if (lane == 0) {
            float r = v + bia;
            if      (s == 0) psc[15] = softplusf(r);
            else if (s == 1) psc[2]  = 1.0f + softplusf(r);
            else if (s == 2) psc[4]  = sigmoidf(r);
            else if (s == 3) psc[16] = softplusf(r);
            else if (s == 4) psc[3]  = 1.0f + softplusf(r);
            else if (s == 5) psc[5]  = sigmoidf(r);
            else if (s < 9)  psc[6 + c] = r;
            else             psc[9 + c] = r;
        }
    }
    __syncthreads();

    if (wv == 0) {
        float v = pk_w[lane] * pk_w[lane];
        #pragma unroll
        for (int m2 = 32; m2; m2 >>= 1) v += __shfl_xor(v, m2);
        if (lane == 0) psc[0] = psc[15] / fmaxf(sqrtf(v), EPSF);
    }
    if (wv == 1) {
        float v = pk_r[lane] * pk_r[lane];
        #pragma unroll
        for (int m2 = 32; m2; m2 >>= 1) v += __shfl_xor(v, m2);
        if (lane == 0) psc[1] = psc[16] / fmaxf(sqrtf(v), EPSF);
    }
    if (wv == 2) {
        float v = pk_r[lane] * pa[lane];
        #pragma unroll
        for (int m2 = 32; m2; m2 >>= 1) v += __shfl_xor(v, m2);
        if (lane == 0) psc[12] = v;
    }
    if (wv == 3) {
        float v = pa[lane] * pa[lane];
        #pragma unroll
        for (int m2 = 32; m2; m2 >>= 1) v += __shfl_xor(v, m2);
        if (lane == 0) psc[13] = v;
    }
    __syncthreads();

    const float4* base = reinterpret_cast<const float4*>(mb + (size_t)b * NN * MM);

    // ---------------- Phase B: 6 summaries/row, 4-deep pipelined ----------
    {
        float kw[4], kr[4], ev[4], av[4];
        #pragma unroll
        for (int j = 0; j < 4; ++j) {
            kw[j] = pk_w[l16 * 4 + j];
            kr[j] = pk_r[l16 * 4 + j];
            ev[j] = pe[l16 * 4 + j];
            av[j] = pa[l16 * 4 + j];
        }
        const float kra_ = psc[12], saa_ = psc[13];

        float4 v0 = base[(0 * 64 + g16) * 16 + l16];
        float4 v1 = base[(1 * 64 + g16) * 16 + l16];
        float4 v2 = base[(2 * 64 + g16) * 16 + l16];
        float4 v3 = base[(3 * 64 + g16) * 16 + l16];

        #pragma unroll 1
        for (int it = 0; it < 28; it += 4) {
            PROC_B(v0, it);     v0 = base[((it + 4) * 64 + g16) * 16 + l16];
            PROC_B(v1, it + 1); v1 = base[((it + 5) * 64 + g16) * 16 + l16];
            PROC_B(v2, it + 2); v2 = base[((it + 6) * 64 + g16) * 16 + l16];
            PROC_B(v3, it + 3); v3 = base[((it + 7) * 64 + g16) * 16 + l16];
        }
        PROC_B(v0, 28); PROC_B(v1, 29); PROC_B(v2, 30); PROC_B(v3, 31);
    }
    __syncthreads();

    // ---------------- Phase C: head 0 (write) ----------------
    {
        const float g = psc[4], gamma = psc[2];
        const float s0c = psc[6], s1c = psc[7], s2c = psc[8];
        const float coef = psc[0];

        float lgr[2], bbr[2];
        float mL = -1e30f, mB = -1e30f;
        #pragma unroll
        for (int k = 0; k < 2; ++k) {
            int i = tid + k * 1024;
            float lw = summ6[i];
            float s0 = summ6[PITCH + i];
            float lg = coef * lw / fmaxf(sqrtf(s0), EPSF);
            lgr[k] = lg; mL = fmaxf(mL, lg);
            float bb = in.p[30][(size_t)b * NN + i]; bbr[k] = bb; mB = fmaxf(mB, bb);
        }
        bredN(mL, mB, true, red);

        float pw[2], pb[2];
        float sL = 0.f, sB = 0.f;
        #pragma unroll
        for (int k = 0; k < 2; ++k) {
            pw[k] = __expf(lgr[k] - mL);
            pb[k] = __expf(bbr[k] - mB);
            sL += pw[k]; sB += pb[k];
        }
        bredN(sL, sB, false, red);
        const float iL = 1.0f / sL, iB = 1.0f / sB;

        #pragma unroll
        for (int k = 0; k < 2; ++k) {
            int i = tid + k * 1024;
            ats[i] = g * pw[k] * iL + (1.0f - g) * pb[k] * iB;
        }
        __syncthreads();

        float pv[2]; float ps = 0.f;
        #pragma unroll
        for (int k = 0; k < 2; ++k) {
            int i = tid + k * 1024;
            float tw = s0c * ats[(i + NN - 1) & (NN - 1)]
                     + s1c * ats[i]
                     + s2c * ats[(i + 1) & (NN - 1)];
            float p = fpowf(tw, gamma);
            pv[k] = p; ps += p;
        }
        float dmy = 0.f;
        bredN(ps, dmy, false, red);
        const float inv = 1.0f / (EPSF + ps);
        #pragma unroll
        for (int k = 0; k < 2; ++k) {
            int i = tid + k * 1024;
            watt[i] = pv[k] * inv;
        }
        __syncthreads();
    }

    // ---------------- Phase C: head 1 (read) ----------------
    {
        const float g = psc[5], gamma = psc[3];
        const float s0c = psc[9], s1c = psc[10], s2c = psc[11];
        const float coef = psc[1];

        float lgr[2], bbr[2];
        float mL = -1e30f, mB = -1e30f;
        #pragma unroll
        for (int k = 0; k < 2; ++k) {
            int i = tid + k * 1024;
            const float w  = watt[i];
            const float s0 = summ6[PITCH + i];
            const float d1 = summ6[2 * PITCH + i];
            const float v1 = summ6[3 * PITCH + i];
            const float u1 = summ6[4 * PITCH + i];
            const float u2 = summ6[5 * PITCH + i];
            const float dot = fmaf(w, v1, d1);
            float nrm2 = s0 + 2.f * w * u1 + w * w * u2;
            nrm2 = fmaxf(nrm2, 0.f);
            float lg = coef * dot / fmaxf(sqrtf(nrm2), EPSF);
            lgr[k] = lg; mL = fmaxf(mL, lg);
            float bb = in.p[29][(size_t)b * NN + i]; bbr[k] = bb; mB = fmaxf(mB, bb);
        }
        bredN(mL, mB, true, red);

        float pw[2], pb[2];
        float sL = 0.f, sB = 0.f;
        #pragma unroll
        for (int k = 0; k < 2; ++k) {
            pw[k] = __expf(lgr[k] - mL);
            pb[k] = __expf(bbr[k] - mB);
            sL += pw[k]; sB += pb[k];
        }
        bredN(sL, sB, false, red);
        const float iL = 1.0f / sL, iB = 1.0f / sB;

        #pragma unroll
        for (int k = 0; k < 2; ++k) {
            int i = tid + k * 1024;
            ats[i] = g * pw[k] * iL + (1.0f - g) * pb[k] * iB;
        }
        __syncthreads();

        float pv[2]; float ps = 0.f;
        #pragma unroll
        for (int k = 0; k < 2; ++k) {
            int i = tid + k * 1024;
            float tw = s0c * ats[(i + NN - 1) & (NN - 1)]
                     + s1c * ats[i]
                     + s2c * ats[(i + 1) & (NN - 1)];
            float p = fpowf(tw, gamma);
            pv[k] = p; ps += p;
        }
        float dmy = 0.f;
        bredN(ps, dmy, false, red);
        const float inv = 1.0f / (EPSF + ps);
        #pragma unroll
        for (int k = 0; k < 2; ++k) {
            int i = tid + k * 1024;
            ratt[i] = pv[k] * inv;
        }
        __syncthreads();
    }

    // ---------------- Phase D: weighted read + output ----------------
    // r = S1 - e.*S2 + t*a;  S1 = sum ra*mb, S2 = sum (ra*w)*mb, t = sum ra*w
    float* wp1 = summ6;            // summaries fully consumed; alias
    float* wp2 = summ6 + 1024;

    float tval = ratt[tid] * watt[tid] + ratt[tid + 1024] * watt[tid + 1024];
    {
        float dmy = 0.f;
        bredN(tval, dmy, false, red);
    }

    {
        float a1[4], a2[4];
        #pragma unroll
        for (int j = 0; j < 4; ++j) { a1[j] = 0.f; a2[j] = 0.f; }

        float4 v0 = base[(0 * 64 + g16) * 16 + l16];
        float4 v1 = base[(1 * 64 + g16) * 16 + l16];
        float4 v2 = base[(2 * 64 + g16) * 16 + l16];
        float4 v3 = base[(3 * 64 + g16) * 16 + l16];

        #pragma unroll 1
        for (int it = 0; it < 28; it += 4) {
            PROC_D(v0, it);     v0 = base[((it + 4) * 64 + g16) * 16 + l16];
            PROC_D(v1, it + 1); v1 = base[((it + 5) * 64 + g16) * 16 + l16];
            PROC_D(v2, it + 2); v2 = base[((it + 6) * 64 + g16) * 16 + l16];
            PROC_D(v3, it + 3); v3 = base[((it + 7) * 64 + g16) * 16 + l16];
        }
        PROC_D(v0, 28); PROC_D(v1, 29); PROC_D(v2, 30); PROC_D(v3, 31);

        // reduce across the wave's 4 groups (xor 16, 32)
        #pragma unroll
        for (int j = 0; j < 4; ++j) {
            a1[j] += __shfl_xor(a1[j], 16);
            a1[j] += __shfl_xor(a1[j], 32);
            a2[j] += __shfl_xor(a2[j], 16);
            a2[j] += __shfl_xor(a2[j], 32);
        }
        if (lane < 16) {
            #pragma unroll
            for (int j = 0; j < 4; ++j) {
                wp1[wv * 64 + lane * 4 + j] = a1[j];
                wp2[wv * 64 + lane * 4 + j] = a2[j];
            }
        }
    }
    __syncthreads();

    if (tid < 64) {
        float S1 = 0.f, S2 = 0.f;
        #pragma unroll
        for (int w8 = 0; w8 < 16; ++w8) {
            S1 += wp1[w8 * 64 + tid];
            S2 += wp2[w8 * 64 + tid];
        }
        rv[tid] = S1 - pe[tid] * S2 + tval * pa[tid];
    }
    __syncthreads();

    if (tid < 64) {
        const float* Wo = in.p[3];
        float o = in.p[4][tid];
        #pragma unroll 4
        for (int m = 0; m < 64; ++m) o = fmaf(rv[m], Wo[m * 64 + tid], o);
        out[(size_t)b * 64 + tid] = sigmoidf(o);
    }
}

// ---------------------------------------------------------------------------
extern "C" void kernel_launch(void* const* d_in, const int* in_sizes, int n_in,
                              void* d_out, int out_size, void* d_ws, size_t ws_size,
                              hipStream_t stream)
{
    Ptrs in;
    for (int i = 0; i < 32; ++i) in.p[i] = (const float*)d_in[i];
    const float* mb = (const float*)d_in[31];

    k_fused<<<BB, 1024, 0, stream>>>(in, mb, (float*)d_out);
}

// Round 12
// 60.090 us; speedup vs baseline: 1.1847x; 1.1847x over previous
//
#include <hip/hip_runtime.h>
#include <hip/hip_bf16.h>
#include <math.h>

#define BB 256
#define NN 2048
#define MM 64
#define INF_ 128
#define HH 100
#define EPSF 1e-8f
#define PITCH 2056   // %32==8 -> SoA summary rows land in staggered banks

struct Ptrs { const float* p[32]; };

__device__ __forceinline__ float softplusf(float x) {
    return fmaxf(x, 0.0f) + log1pf(__expf(-fabsf(x)));
}
__device__ __forceinline__ float sigmoidf(float x) {
    return 1.0f / (1.0f + __expf(-x));
}
// fast positive-base pow; |rel err| ~1e-6, far under the 1.36e-2 threshold
__device__ __forceinline__ float fpowf(float x, float g) {
    return __expf(g * __logf(x));
}

// block-wide (16 waves) reduction of two values
__device__ __forceinline__ void bredN(float& a, float& b, bool ismax, float* red)
{
    #pragma unroll
    for (int m = 32; m; m >>= 1) {
        float ta = __shfl_xor(a, m), tb = __shfl_xor(b, m);
        if (ismax) { a = fmaxf(a, ta); b = fmaxf(b, tb); }
        else       { a += ta; b += tb; }
    }
    const int wid = threadIdx.x >> 6;
    if ((threadIdx.x & 63) == 0) { red[wid] = a; red[16 + wid] = b; }
    __syncthreads();
    float ra = red[0], rb = red[16];
    #pragma unroll
    for (int w = 1; w < 16; ++w) {
        if (ismax) { ra = fmaxf(ra, red[w]); rb = fmaxf(rb, red[16 + w]); }
        else       { ra += red[w]; rb += red[16 + w]; }
    }
    __syncthreads();
    a = ra; b = rb;
}

// ---------------------------------------------------------------------------
// One block per batch row b (1024 thr = 16 waves; grid == CU count).
// Round-7 structure (best measured: 63.0 us) with exactly two changes:
//   - summaries stored SoA 6 x PITCH (conflict-free phase-C reads) instead
//     of AoS 8/row (4-way conflicts, 1.05M conflict cycles)
//   - phase-C logits in registers instead of an LDS array
// Streaming loops (B, D) are byte-identical to round 7: 8-lane groups,
// 8 floats/lane, compiler-scheduled unroll-4 (manual pipelines regressed,
// rounds 9-11).
// ---------------------------------------------------------------------------
__global__ void __launch_bounds__(1024) k_fused(Ptrs in,
                                                const float* __restrict__ mb,
                                                float* __restrict__ out)
{
    __shared__ float xs[INF_];
    __shared__ float hs[HH];
    __shared__ float pk_w[MM], pk_r[MM], pe[MM], pa[MM];
    __shared__ float psc[20];
    __shared__ float summ6[6 * PITCH];   // 49.3 KB SoA
    __shared__ float ats[NN];
    __shared__ float watt[NN];
    __shared__ float ratt[NN];
    __shared__ float red[32];
    __shared__ float wp1[16 * 64];
    __shared__ float wp2[16 * 64];
    __shared__ float rv[64];

    const int b = blockIdx.x, tid = threadIdx.x;
    const int lane = tid & 63, wv = tid >> 6;       // 16 waves
    const int grp = tid >> 3, l8 = tid & 7;         // 128 groups of 8

    // ---------------- Phase A: params ----------------
    if (tid < INF_) xs[tid] = in.p[0][b * INF_ + tid];
    __syncthreads();

    if (tid < HH) {
        const float* Wc = in.p[1];
        float acc = in.p[2][tid];
        #pragma unroll 8
        for (int i = 0; i < INF_; ++i)
            acc = fmaf(xs[i], Wc[i * HH + tid], acc);
        hs[tid] = acc;
    }
    __syncthreads();

    if (wv < 4) {
        const int m = lane;
        const float* W; const float* bi;
        if      (wv == 0) { W = in.p[23]; bi = in.p[24]; }
        else if (wv == 1) { W = in.p[13]; bi = in.p[14]; }
        else if (wv == 2) { W = in.p[25]; bi = in.p[26]; }
        else              { W = in.p[27]; bi = in.p[28]; }
        float acc = bi[m];
        #pragma unroll 10
        for (int j = 0; j < HH; ++j)
            acc = fmaf(hs[j], W[j * 64 + m], acc);
        if      (wv == 0) pk_w[m] = acc;
        else if (wv == 1) pk_r[m] = acc;
        else if (wv == 2) pe[m]   = sigmoidf(acc);
        else              pa[m]   = acc;
    } else {
        const int s = wv - 4;
        const float* W; float bia; int strd = 1, c = 0;
        if      (s == 0) { W = in.p[15]; bia = in.p[16][0]; }
        else if (s == 1) { W = in.p[17]; bia = in.p[18][0]; }
        else if (s == 2) { W = in.p[19]; bia = in.p[20][0]; }
        else if (s == 3) { W = in.p[5];  bia = in.p[6][0]; }
        else if (s == 4) { W = in.p[7];  bia = in.p[8][0]; }
        else if (s == 5) { W = in.p[9];  bia = in.p[10][0]; }
        else if (s < 9)  { W = in.p[21]; c = s - 6; bia = in.p[22][c]; strd = 3; }
        else             { W = in.p[11]; c = s - 9; bia = in.p[12][c]; strd = 3; }
        float v = 0.f;
        if (lane < HH)      v = hs[lane] * W[lane * strd + c];
        if (lane < HH - 64) v = fmaf(hs[lane + 64], W[(lane + 64) * strd + c], v);
        #pragma unroll
        for (int m2 = 32; m2; m2 >>= 1) v += __shfl_xor(v, m2);
        if (lane == 0) {
            float r = v + bia;
            if      (s == 0) psc[15] = softplusf(r);
            else if (s == 1) psc[2]  = 1.0f + softplusf(r);
            else if (s == 2) psc[4]  = sigmoidf(r);
            else if (s == 3) psc[16] = softplusf(r);
            else if (s == 4) psc[3]  = 1.0f + softplusf(r);
            else if (s == 5) psc[5]  = sigmoidf(r);
            else if (s < 9)  psc[6 + c] = r;
            else             psc[9 + c] = r;
        }
    }
    __syncthreads();

    if (wv == 0) {
        float v = pk_w[lane] * pk_w[lane];
        #pragma unroll
        for (int m2 = 32; m2; m2 >>= 1) v += __shfl_xor(v, m2);
        if (lane == 0) psc[0] = psc[15] / fmaxf(sqrtf(v), EPSF);
    }
    if (wv == 1) {
        float v = pk_r[lane] * pk_r[lane];
        #pragma unroll
        for (int m2 = 32; m2; m2 >>= 1) v += __shfl_xor(v, m2);
        if (lane == 0) psc[1] = psc[16] / fmaxf(sqrtf(v), EPSF);
    }
    if (wv == 2) {
        float v = pk_r[lane] * pa[lane];
        #pragma unroll
        for (int m2 = 32; m2; m2 >>= 1) v += __shfl_xor(v, m2);
        if (lane == 0) psc[12] = v;
    }
    if (wv == 3) {
        float v = pa[lane] * pa[lane];
        #pragma unroll
        for (int m2 = 32; m2; m2 >>= 1) v += __shfl_xor(v, m2);
        if (lane == 0) psc[13] = v;
    }
    __syncthreads();

    const float4* base = reinterpret_cast<const float4*>(mb + (size_t)b * NN * MM);

    // ---------------- Phase B: 6 summaries/row (round-7 streaming) --------
    {
        float kw[8], kr[8], ev[8], av[8];
        #pragma unroll
        for (int j = 0; j < 8; ++j) {
            kw[j] = pk_w[l8 * 8 + j];
            kr[j] = pk_r[l8 * 8 + j];
            ev[j] = pe[l8 * 8 + j];
            av[j] = pa[l8 * 8 + j];
        }
        const float kra_ = psc[12], saa_ = psc[13];

        #pragma unroll 4
        for (int it = 0; it < 16; ++it) {
            const int n = it * 128 + grp;
            float4 v0 = base[n * 16 + 2 * l8];
            float4 v1 = base[n * 16 + 2 * l8 + 1];
            float f[8] = {v0.x, v0.y, v0.z, v0.w, v1.x, v1.y, v1.z, v1.w};

            float acc[8];
            #pragma unroll
            for (int j = 0; j < 8; ++j) acc[j] = 0.f;
            #pragma unroll
            for (int j = 0; j < 8; ++j) {
                const float m = f[j];
                const float em = ev[j] * m;
                acc[0] = fmaf(kw[j], m, acc[0]);                  // lw
                acc[1] = fmaf(m, m, acc[1]);                      // s0
                acc[2] = fmaf(kr[j], m, acc[2]);                  // d1
                acc[3] = fmaf(kr[j], em, acc[3]);                 // d2 (raw)
                acc[4] = fmaf(m, av[j] - em, acc[4]);             // u1
                acc[5] = fmaf(em, fmaf(-2.f, av[j], em), acc[5]); // u2 (raw)
            }

            // transposing butterfly: lane l8 ends with acc[l8]
            float k1[4];
            #pragma unroll
            for (int k = 0; k < 4; ++k) {
                float snd = (l8 & 1) ? acc[2 * k] : acc[2 * k + 1];
                float rcv = __shfl_xor(snd, 1);
                k1[k] = ((l8 & 1) ? acc[2 * k + 1] : acc[2 * k]) + rcv;
            }
            float k2[2];
            #pragma unroll
            for (int k = 0; k < 2; ++k) {
                float snd = (l8 & 2) ? k1[2 * k] : k1[2 * k + 1];
                float rcv = __shfl_xor(snd, 2);
                k2[k] = ((l8 & 2) ? k1[2 * k + 1] : k1[2 * k]) + rcv;
            }
            float snd = (l8 & 4) ? k2[0] : k2[1];
            float rcv = __shfl_xor(snd, 4);
            float tot = ((l8 & 4) ? k2[1] : k2[0]) + rcv;

            if (l8 == 3) tot = kra_ - tot;        // v1 = kra - d2
            if (l8 == 5) tot += saa_;             // u2 = raw + saa
            if (l8 < 6) summ6[l8 * PITCH + n] = tot;
        }
    }
    __syncthreads();

    // ---------------- Phase C: head 0 (write) ----------------
    {
        const float g = psc[4], gamma = psc[2];
        const float s0c = psc[6], s1c = psc[7], s2c = psc[8];
        const float coef = psc[0];

        float lgr[2], bbr[2];
        float mL = -1e30f, mB = -1e30f;
        #pragma unroll
        for (int k = 0; k < 2; ++k) {
            int i = tid + k * 1024;
            float lw = summ6[i];
            float s0 = summ6[PITCH + i];
            float lg = coef * lw / fmaxf(sqrtf(s0), EPSF);
            lgr[k] = lg; mL = fmaxf(mL, lg);
            float bb = in.p[30][(size_t)b * NN + i]; bbr[k] = bb; mB = fmaxf(mB, bb);
        }
        bredN(mL, mB, true, red);

        float pw[2], pb[2];
        float sL = 0.f, sB = 0.f;
        #pragma unroll
        for (int k = 0; k < 2; ++k) {
            pw[k] = __expf(lgr[k] - mL);
            pb[k] = __expf(bbr[k] - mB);
            sL += pw[k]; sB += pb[k];
        }
        bredN(sL, sB, false, red);
        const float iL = 1.0f / sL, iB = 1.0f / sB;

        #pragma unroll
        for (int k = 0; k < 2; ++k) {
            int i = tid + k * 1024;
            ats[i] = g * pw[k] * iL + (1.0f - g) * pb[k] * iB;
        }
        __syncthreads();

        float pv[2]; float ps = 0.f;
        #pragma unroll
        for (int k = 0; k < 2; ++k) {
            int i = tid + k * 1024;
            float tw = s0c * ats[(i + NN - 1) & (NN - 1)]
                     + s1c * ats[i]
                     + s2c * ats[(i + 1) & (NN - 1)];
            float p = fpowf(tw, gamma);
            pv[k] = p; ps += p;
        }
        float dmy = 0.f;
        bredN(ps, dmy, false, red);
        const float inv = 1.0f / (EPSF + ps);
        #pragma unroll
        for (int k = 0; k < 2; ++k) {
            int i = tid + k * 1024;
            watt[i] = pv[k] * inv;
        }
        __syncthreads();
    }

    // ---------------- Phase C: head 1 (read) ----------------
    {
        const float g = psc[5], gamma = psc[3];
        const float s0c = psc[9], s1c = psc[10], s2c = psc[11];
        const float coef = psc[1];

        float lgr[2], bbr[2];
        float mL = -1e30f, mB = -1e30f;
        #pragma unroll
        for (int k = 0; k < 2; ++k) {
            int i = tid + k * 1024;
            const float w  = watt[i];
            const float s0 = summ6[PITCH + i];
            const float d1 = summ6[2 * PITCH + i];
            const float v1 = summ6[3 * PITCH + i];
            const float u1 = summ6[4 * PITCH + i];
            const float u2 = summ6[5 * PITCH + i];
            const float dot = fmaf(w, v1, d1);
            float nrm2 = s0 + 2.f * w * u1 + w * w * u2;
            nrm2 = fmaxf(nrm2, 0.f);
            float lg = coef * dot / fmaxf(sqrtf(nrm2), EPSF);
            lgr[k] = lg; mL = fmaxf(mL, lg);
            float bb = in.p[29][(size_t)b * NN + i]; bbr[k] = bb; mB = fmaxf(mB, bb);
        }
        bredN(mL, mB, true, red);

        float pw[2], pb[2];
        float sL = 0.f, sB = 0.f;
        #pragma unroll
        for (int k = 0; k < 2; ++k) {
            pw[k] = __expf(lgr[k] - mL);
            pb[k] = __expf(bbr[k] - mB);
            sL += pw[k]; sB += pb[k];
        }
        bredN(sL, sB, false, red);
        const float iL = 1.0f / sL, iB = 1.0f / sB;

        #pragma unroll
        for (int k = 0; k < 2; ++k) {
            int i = tid + k * 1024;
            ats[i] = g * pw[k] * iL + (1.0f - g) * pb[k] * iB;
        }
        __syncthreads();

        float pv[2]; float ps = 0.f;
        #pragma unroll
        for (int k = 0; k < 2; ++k) {
            int i = tid + k * 1024;
            float tw = s0c * ats[(i + NN - 1) & (NN - 1)]
                     + s1c * ats[i]
                     + s2c * ats[(i + 1) & (NN - 1)];
            float p = fpowf(tw, gamma);
            pv[k] = p; ps += p;
        }
        float dmy = 0.f;
        bredN(ps, dmy, false, red);
        const float inv = 1.0f / (EPSF + ps);
        #pragma unroll
        for (int k = 0; k < 2; ++k) {
            int i = tid + k * 1024;
            ratt[i] = pv[k] * inv;
        }
        __syncthreads();
    }

    // ---------------- Phase D: weighted read + output (round-7) ----------
    // r = S1 - e.*S2 + t*a;  S1 = sum ra*mb, S2 = sum (ra*w)*mb, t = sum ra*w
    float tval = ratt[tid] * watt[tid] + ratt[tid + 1024] * watt[tid + 1024];
    {
        float dmy = 0.f;
        bredN(tval, dmy, false, red);
    }

    {
        float a1[8], a2[8];
        #pragma unroll
        for (int j = 0; j < 8; ++j) { a1[j] = 0.f; a2[j] = 0.f; }

        #pragma unroll 4
        for (int it = 0; it < 16; ++it) {
            const int n = it * 128 + grp;
            const float c1 = ratt[n];
            const float c2 = c1 * watt[n];
            float4 v0 = base[n * 16 + 2 * l8];
            float4 v1 = base[n * 16 + 2 * l8 + 1];
            float f[8] = {v0.x, v0.y, v0.z, v0.w, v1.x, v1.y, v1.z, v1.w};
            #pragma unroll
            for (int j = 0; j < 8; ++j) {
                a1[j] = fmaf(c1, f[j], a1[j]);
                a2[j] = fmaf(c2, f[j], a2[j]);
            }
        }
        // reduce across the 8 groups within each wave
        #pragma unroll
        for (int j = 0; j < 8; ++j) {
            #pragma unroll
            for (int mask = 8; mask < 64; mask <<= 1) {
                a1[j] += __shfl_xor(a1[j], mask);
                a2[j] += __shfl_xor(a2[j], mask);
            }
        }
        if (lane < 8) {
            #pragma unroll
            for (int j = 0; j < 8; ++j) {
                wp1[wv * 64 + lane * 8 + j] = a1[j];
                wp2[wv * 64 + lane * 8 + j] = a2[j];
            }
        }
    }
    __syncthreads();

    if (tid < 64) {
        float S1 = 0.f, S2 = 0.f;
        #pragma unroll
        for (int w8 = 0; w8 < 16; ++w8) {
            S1 += wp1[w8 * 64 + tid];
            S2 += wp2[w8 * 64 + tid];
        }
        rv[tid] = S1 - pe[tid] * S2 + tval * pa[tid];
    }
    __syncthreads();

    if (tid < 64) {
        const float* Wo = in.p[3];
        float o = in.p[4][tid];
        #pragma unroll 4
        for (int m = 0; m < 64; ++m) o = fmaf(rv[m], Wo[m * 64 + tid], o);
        out[(size_t)b * 64 + tid] = sigmoidf(o);
    }
}

// ---------------------------------------------------------------------------
extern "C" void kernel_launch(void* const* d_in, const int* in_sizes, int n_in,
                              void* d_out, int out_size, void* d_ws, size_t ws_size,
                              hipStream_t stream)
{
    Ptrs in;
    for (int i = 0; i < 32; ++i) in.p[i] = (const float*)d_in[i];
    const float* mb = (const float*)d_in[31];

    k_fused<<<BB, 1024, 0, stream>>>(in, mb, (float*)d_out);
}

// Round 13
// 58.902 us; speedup vs baseline: 1.2086x; 1.0202x over previous
//
#include <hip/hip_runtime.h>
#include <hip/hip_bf16.h>
#include <math.h>

#define BB 256
#define NN 2048
#define MM 64
#define INF_ 128
#define HH 100
#define EPSF 1e-8f
#define PITCH 2056   // %32==8 -> SoA summary rows land in staggered banks
#define CPITCH 68    // cached-row pitch: 272 B, 16B-aligned, bank offset 4/row

struct Ptrs { const float* p[32]; };

__device__ __forceinline__ float softplusf(float x) {
    return fmaxf(x, 0.0f) + log1pf(__expf(-fabsf(x)));
}
__device__ __forceinline__ float sigmoidf(float x) {
    return 1.0f / (1.0f + __expf(-x));
}
// fast positive-base pow; |rel err| ~1e-6, far under the 1.36e-2 threshold
__device__ __forceinline__ float fpowf(float x, float g) {
    return __expf(g * __logf(x));
}

// block-wide (16 waves) reduction of two values
__device__ __forceinline__ void bredN(float& a, float& b, bool ismax, float* red)
{
    #pragma unroll
    for (int m = 32; m; m >>= 1) {
        float ta = __shfl_xor(a, m), tb = __shfl_xor(b, m);
        if (ismax) { a = fmaxf(a, ta); b = fmaxf(b, tb); }
        else       { a += ta; b += tb; }
    }
    const int wid = threadIdx.x >> 6;
    if ((threadIdx.x & 63) == 0) { red[wid] = a; red[16 + wid] = b; }
    __syncthreads();
    float ra = red[0], rb = red[16];
    #pragma unroll
    for (int w = 1; w < 16; ++w) {
        if (ismax) { ra = fmaxf(ra, red[w]); rb = fmaxf(rb, red[16 + w]); }
        else       { ra += red[w]; rb += red[16 + w]; }
    }
    __syncthreads();
    a = ra; b = rb;
}

// ---------------------------------------------------------------------------
// One block per batch row b (1024 thr = 16 waves; grid == CU count).
// Round-12 structure (best: 60.1 us) + one change: phase B parks the last
// 256 mb rows in LDS (69.6 KB, pitch 68) so phase D re-reads only 14/16 of
// the slice from global. Streaming loop structure otherwise byte-identical
// (hand pipelines regressed in r9-r11; compiler unroll-4 wins).
// ---------------------------------------------------------------------------
__global__ void __launch_bounds__(1024) k_fused(Ptrs in,
                                                const float* __restrict__ mb,
                                                float* __restrict__ out)
{
    __shared__ float xs[INF_];
    __shared__ float hs[HH];
    __shared__ float pk_w[MM], pk_r[MM], pe[MM], pa[MM];
    __shared__ float psc[20];
    __shared__ float summ6[6 * PITCH];   // 49.3 KB SoA
    __shared__ float ats[NN];
    __shared__ float watt[NN];
    __shared__ float ratt[NN];
    __shared__ float red[32];
    __shared__ float wp1[16 * 64];
    __shared__ float wp2[16 * 64];
    __shared__ float rv[64];
    __shared__ __align__(16) float mbc[256 * CPITCH];  // 69.6 KB row cache

    const int b = blockIdx.x, tid = threadIdx.x;
    const int lane = tid & 63, wv = tid >> 6;       // 16 waves
    const int grp = tid >> 3, l8 = tid & 7;         // 128 groups of 8

    // ---------------- Phase A: params ----------------
    if (tid < INF_) xs[tid] = in.p[0][b * INF_ + tid];
    __syncthreads();

    if (tid < HH) {
        const float* Wc = in.p[1];
        float acc = in.p[2][tid];
        #pragma unroll 8
        for (int i = 0; i < INF_; ++i)
            acc = fmaf(xs[i], Wc[i * HH + tid], acc);
        hs[tid] = acc;
    }
    __syncthreads();

    if (wv < 4) {
        const int m = lane;
        const float* W; const float* bi;
        if      (wv == 0) { W = in.p[23]; bi = in.p[24]; }
        else if (wv == 1) { W = in.p[13]; bi = in.p[14]; }
        else if (wv == 2) { W = in.p[25]; bi = in.p[26]; }
        else              { W = in.p[27]; bi = in.p[28]; }
        float acc = bi[m];
        #pragma unroll 10
        for (int j = 0; j < HH; ++j)
            acc = fmaf(hs[j], W[j * 64 + m], acc);
        if      (wv == 0) pk_w[m] = acc;
        else if (wv == 1) pk_r[m] = acc;
        else if (wv == 2) pe[m]   = sigmoidf(acc);
        else              pa[m]   = acc;
    } else {
        const int s = wv - 4;
        const float* W; float bia; int strd = 1, c = 0;
        if      (s == 0) { W = in.p[15]; bia = in.p[16][0]; }
        else if (s == 1) { W = in.p[17]; bia = in.p[18][0]; }
        else if (s == 2) { W = in.p[19]; bia = in.p[20][0]; }
        else if (s == 3) { W = in.p[5];  bia = in.p[6][0]; }
        else if (s == 4) { W = in.p[7];  bia = in.p[8][0]; }
        else if (s == 5) { W = in.p[9];  bia = in.p[10][0]; }
        else if (s < 9)  { W = in.p[21]; c = s - 6; bia = in.p[22][c]; strd = 3; }
        else             { W = in.p[11]; c = s - 9; bia = in.p[12][c]; strd = 3; }
        float v = 0.f;
        if (lane < HH)      v = hs[lane] * W[lane * strd + c];
        if (lane < HH - 64) v = fmaf(hs[lane + 64], W[(lane + 64) * strd + c], v);
        #pragma unroll
        for (int m2 = 32; m2; m2 >>= 1) v += __shfl_xor(v, m2);
        if (lane == 0) {
            float r = v + bia;
            if      (s == 0) psc[15] = softplusf(r);
            else if (s == 1) psc[2]  = 1.0f + softplusf(r);
            else if (s == 2) psc[4]  = sigmoidf(r);
            else if (s == 3) psc[16] = softplusf(r);
            else if (s == 4) psc[3]  = 1.0f + softplusf(r);
            else if (s == 5) psc[5]  = sigmoidf(r);
            else if (s < 9)  psc[6 + c] = r;
            else             psc[9 + c] = r;
        }
    }
    __syncthreads();

    if (wv == 0) {
        float v = pk_w[lane] * pk_w[lane];
        #pragma unroll
        for (int m2 = 32; m2; m2 >>= 1) v += __shfl_xor(v, m2);
        if (lane == 0) psc[0] = psc[15] / fmaxf(sqrtf(v), EPSF);
    }
    if (wv == 1) {
        float v = pk_r[lane] * pk_r[lane];
        #pragma unroll
        for (int m2 = 32; m2; m2 >>= 1) v += __shfl_xor(v, m2);
        if (lane == 0) psc[1] = psc[16] / fmaxf(sqrtf(v), EPSF);
    }
    if (wv == 2) {
        float v = pk_r[lane] * pa[lane];
        #pragma unroll
        for (int m2 = 32; m2; m2 >>= 1) v += __shfl_xor(v, m2);
        if (lane == 0) psc[12] = v;
    }
    if (wv == 3) {
        float v = pa[lane] * pa[lane];
        #pragma unroll
        for (int m2 = 32; m2; m2 >>= 1) v += __shfl_xor(v, m2);
        if (lane == 0) psc[13] = v;
    }
    __syncthreads();

    const float4* base = reinterpret_cast<const float4*>(mb + (size_t)b * NN * MM);

    // ---------------- Phase B: 6 summaries/row + park last 256 rows -------
    {
        float kw[8], kr[8], ev[8], av[8];
        #pragma unroll
        for (int j = 0; j < 8; ++j) {
            kw[j] = pk_w[l8 * 8 + j];
            kr[j] = pk_r[l8 * 8 + j];
            ev[j] = pe[l8 * 8 + j];
            av[j] = pa[l8 * 8 + j];
        }
        const float kra_ = psc[12], saa_ = psc[13];

        #pragma unroll 4
        for (int it = 0; it < 16; ++it) {
            const int n = it * 128 + grp;
            float4 v0 = base[n * 16 + 2 * l8];
            float4 v1 = base[n * 16 + 2 * l8 + 1];

            if (it >= 14) {   // compile-time after unroll: park row in LDS
                float4* c = reinterpret_cast<float4*>(
                    &mbc[((it - 14) * 128 + grp) * CPITCH + l8 * 8]);
                c[0] = v0; c[1] = v1;
            }

            float f[8] = {v0.x, v0.y, v0.z, v0.w, v1.x, v1.y, v1.z, v1.w};

            float acc[8];
            #pragma unroll
            for (int j = 0; j < 8; ++j) acc[j] = 0.f;
            #pragma unroll
            for (int j = 0; j < 8; ++j) {
                const float m = f[j];
                const float em = ev[j] * m;
                acc[0] = fmaf(kw[j], m, acc[0]);                  // lw
                acc[1] = fmaf(m, m, acc[1]);                      // s0
                acc[2] = fmaf(kr[j], m, acc[2]);                  // d1
                acc[3] = fmaf(kr[j], em, acc[3]);                 // d2 (raw)
                acc[4] = fmaf(m, av[j] - em, acc[4]);             // u1
                acc[5] = fmaf(em, fmaf(-2.f, av[j], em), acc[5]); // u2 (raw)
            }

            // transposing butterfly: lane l8 ends with acc[l8]
            float k1[4];
            #pragma unroll
            for (int k = 0; k < 4; ++k) {
                float snd = (l8 & 1) ? acc[2 * k] : acc[2 * k + 1];
                float rcv = __shfl_xor(snd, 1);
                k1[k] = ((l8 & 1) ? acc[2 * k + 1] : acc[2 * k]) + rcv;
            }
            float k2[2];
            #pragma unroll
            for (int k = 0; k < 2; ++k) {
                float snd = (l8 & 2) ? k1[2 * k] : k1[2 * k + 1];
                float rcv = __shfl_xor(snd, 2);
                k2[k] = ((l8 & 2) ? k1[2 * k + 1] : k1[2 * k]) + rcv;
            }
            float snd = (l8 & 4) ? k2[0] : k2[1];
            float rcv = __shfl_xor(snd, 4);
            float tot = ((l8 & 4) ? k2[1] : k2[0]) + rcv;

            if (l8 == 3) tot = kra_ - tot;        // v1 = kra - d2
            if (l8 == 5) tot += saa_;             // u2 = raw + saa
            if (l8 < 6) summ6[l8 * PITCH + n] = tot;
        }
    }
    __syncthreads();

    // ---------------- Phase C: head 0 (write) ----------------
    {
        const float g = psc[4], gamma = psc[2];
        const float s0c = psc[6], s1c = psc[7], s2c = psc[8];
        const float coef = psc[0];

        float lgr[2], bbr[2];
        float mL = -1e30f, mB = -1e30f;
        #pragma unroll
        for (int k = 0; k < 2; ++k) {
            int i = tid + k * 1024;
            float lw = summ6[i];
            float s0 = summ6[PITCH + i];
            float lg = coef * lw / fmaxf(sqrtf(s0), EPSF);
            lgr[k] = lg; mL = fmaxf(mL, lg);
            float bb = in.p[30][(size_t)b * NN + i]; bbr[k] = bb; mB = fmaxf(mB, bb);
        }
        bredN(mL, mB, true, red);

        float pw[2], pb[2];
        float sL = 0.f, sB = 0.f;
        #pragma unroll
        for (int k = 0; k < 2; ++k) {
            pw[k] = __expf(lgr[k] - mL);
            pb[k] = __expf(bbr[k] - mB);
            sL += pw[k]; sB += pb[k];
        }
        bredN(sL, sB, false, red);
        const float iL = 1.0f / sL, iB = 1.0f / sB;

        #pragma unroll
        for (int k = 0; k < 2; ++k) {
            int i = tid + k * 1024;
            ats[i] = g * pw[k] * iL + (1.0f - g) * pb[k] * iB;
        }
        __syncthreads();

        float pv[2]; float ps = 0.f;
        #pragma unroll
        for (int k = 0; k < 2; ++k) {
            int i = tid + k * 1024;
            float tw = s0c * ats[(i + NN - 1) & (NN - 1)]
                     + s1c * ats[i]
                     + s2c * ats[(i + 1) & (NN - 1)];
            float p = fpowf(tw, gamma);
            pv[k] = p; ps += p;
        }
        float dmy = 0.f;
        bredN(ps, dmy, false, red);
        const float inv = 1.0f / (EPSF + ps);
        #pragma unroll
        for (int k = 0; k < 2; ++k) {
            int i = tid + k * 1024;
            watt[i] = pv[k] * inv;
        }
        __syncthreads();
    }

    // ---------------- Phase C: head 1 (read) ----------------
    {
        const float g = psc[5], gamma = psc[3];
        const float s0c = psc[9], s1c = psc[10], s2c = psc[11];
        const float coef = psc[1];

        float lgr[2], bbr[2];
        float mL = -1e30f, mB = -1e30f;
        #pragma unroll
        for (int k = 0; k < 2; ++k) {
            int i = tid + k * 1024;
            const float w  = watt[i];
            const float s0 = summ6[PITCH + i];
            const float d1 = summ6[2 * PITCH + i];
            const float v1 = summ6[3 * PITCH + i];
            const float u1 = summ6[4 * PITCH + i];
            const float u2 = summ6[5 * PITCH + i];
            const float dot = fmaf(w, v1, d1);
            float nrm2 = s0 + 2.f * w * u1 + w * w * u2;
            nrm2 = fmaxf(nrm2, 0.f);
            float lg = coef * dot / fmaxf(sqrtf(nrm2), EPSF);
            lgr[k] = lg; mL = fmaxf(mL, lg);
            float bb = in.p[29][(size_t)b * NN + i]; bbr[k] = bb; mB = fmaxf(mB, bb);
        }
        bredN(mL, mB, true, red);

        float pw[2], pb[2];
        float sL = 0.f, sB = 0.f;
        #pragma unroll
        for (int k = 0; k < 2; ++k) {
            pw[k] = __expf(lgr[k] - mL);
            pb[k] = __expf(bbr[k] - mB);
            sL += pw[k]; sB += pb[k];
        }
        bredN(sL, sB, false, red);
        const float iL = 1.0f / sL, iB = 1.0f / sB;

        #pragma unroll
        for (int k = 0; k < 2; ++k) {
            int i = tid + k * 1024;
            ats[i] = g * pw[k] * iL + (1.0f - g) * pb[k] * iB;
        }
        __syncthreads();

        float pv[2]; float ps = 0.f;
        #pragma unroll
        for (int k = 0; k < 2; ++k) {
            int i = tid + k * 1024;
            float tw = s0c * ats[(i + NN - 1) & (NN - 1)]
                     + s1c * ats[i]
                     + s2c * ats[(i + 1) & (NN - 1)];
            float p = fpowf(tw, gamma);
            pv[k] = p; ps += p;
        }
        float dmy = 0.f;
        bredN(ps, dmy, false, red);
        const float inv = 1.0f / (EPSF + ps);
        #pragma unroll
        for (int k = 0; k < 2; ++k) {
            int i = tid + k * 1024;
            ratt[i] = pv[k] * inv;
        }
        __syncthreads();
    }

    // ---------------- Phase D: weighted read + output ----------------
    // r = S1 - e.*S2 + t*a;  S1 = sum ra*mb, S2 = sum (ra*w)*mb, t = sum ra*w
    float tval = ratt[tid] * watt[tid] + ratt[tid + 1024] * watt[tid + 1024];
    {
        float dmy = 0.f;
        bredN(tval, dmy, false, red);
    }

    {
        float a1[8], a2[8];
        #pragma unroll
        for (int j = 0; j < 8; ++j) { a1[j] = 0.f; a2[j] = 0.f; }

        // rows 0..1791 from global (L3-warm)
        #pragma unroll 4
        for (int it = 0; it < 14; ++it) {
            const int n = it * 128 + grp;
            const float c1 = ratt[n];
            const float c2 = c1 * watt[n];
            float4 v0 = base[n * 16 + 2 * l8];
            float4 v1 = base[n * 16 + 2 * l8 + 1];
            float f[8] = {v0.x, v0.y, v0.z, v0.w, v1.x, v1.y, v1.z, v1.w};
            #pragma unroll
            for (int j = 0; j < 8; ++j) {
                a1[j] = fmaf(c1, f[j], a1[j]);
                a2[j] = fmaf(c2, f[j], a2[j]);
            }
        }
        // rows 1792..2047 from the LDS cache parked in phase B
        #pragma unroll
        for (int it = 14; it < 16; ++it) {
            const int n = it * 128 + grp;
            const float c1 = ratt[n];
            const float c2 = c1 * watt[n];
            const float4* c = reinterpret_cast<const float4*>(
                &mbc[((it - 14) * 128 + grp) * CPITCH + l8 * 8]);
            float4 v0 = c[0], v1 = c[1];
            float f[8] = {v0.x, v0.y, v0.z, v0.w, v1.x, v1.y, v1.z, v1.w};
            #pragma unroll
            for (int j = 0; j < 8; ++j) {
                a1[j] = fmaf(c1, f[j], a1[j]);
                a2[j] = fmaf(c2, f[j], a2[j]);
            }
        }

        // reduce across the 8 groups within each wave
        #pragma unroll
        for (int j = 0; j < 8; ++j) {
            #pragma unroll
            for (int mask = 8; mask < 64; mask <<= 1) {
                a1[j] += __shfl_xor(a1[j], mask);
                a2[j] += __shfl_xor(a2[j], mask);
            }
        }
        if (lane < 8) {
            #pragma unroll
            for (int j = 0; j < 8; ++j) {
                wp1[wv * 64 + lane * 8 + j] = a1[j];
                wp2[wv * 64 + lane * 8 + j] = a2[j];
            }
        }
    }
    __syncthreads();

    if (tid < 64) {
        float S1 = 0.f, S2 = 0.f;
        #pragma unroll
        for (int w8 = 0; w8 < 16; ++w8) {
            S1 += wp1[w8 * 64 + tid];
            S2 += wp2[w8 * 64 + tid];
        }
        rv[tid] = S1 - pe[tid] * S2 + tval * pa[tid];
    }
    __syncthreads();

    if (tid < 64) {
        const float* Wo = in.p[3];
        float o = in.p[4][tid];
        #pragma unroll 4
        for (int m = 0; m < 64; ++m) o = fmaf(rv[m], Wo[m * 64 + tid], o);
        out[(size_t)b * 64 + tid] = sigmoidf(o);
    }
}

// ---------------------------------------------------------------------------
extern "C" void kernel_launch(void* const* d_in, const int* in_sizes, int n_in,
                              void* d_out, int out_size, void* d_ws, size_t ws_size,
                              hipStream_t stream)
{
    Ptrs in;
    for (int i = 0; i < 32; ++i) in.p[i] = (const float*)d_in[i];
    const float* mb = (const float*)d_in[31];

    k_fused<<<BB, 1024, 0, stream>>>(in, mb, (float*)d_out);
}